// Round 22
// baseline (4751.574 us; speedup 1.0000x reference)
//
#include <hip/hip_runtime.h>
#include <math.h>

#define B_ 8
#define N_ 1024
#define D_ 512
#define BAND_ELEMS (B_ * N_ * D_)          // 4194304 = 2^22
#define OUT_MAIN (8L * BAND_ELEMS)         // 33554432
#define NCALLS 19

struct Ptrs8 { const float* p[8]; };
struct CallTab { int qi[NCALLS]; int ki[NCALLS]; };
struct MergeTab { int ncalls[8]; int calls[8][3]; int kis[NCALLS]; float wts[NCALLS]; };

typedef __attribute__((ext_vector_type(8))) short bf16x8;
typedef __attribute__((ext_vector_type(8))) ushort ushort8;
typedef __attribute__((ext_vector_type(4))) float f32x4;

__device__ __forceinline__ ushort f2bf_rne(float x) {
  uint u = __float_as_uint(x);
  return (ushort)((u + 0x7fffu + ((u >> 16) & 1u)) >> 16);
}
__device__ __forceinline__ float bf2f(ushort h) {
  return __uint_as_float(((uint)h) << 16);
}

#define GLOAD16(gsrc, ldst)                                                   \
  __builtin_amdgcn_global_load_lds(                                          \
      (const __attribute__((address_space(1))) void*)(gsrc),                 \
      (__attribute__((address_space(3))) void*)(ldst), 16, 0, 0)
#define GLOAD4(gsrc, ldst)                                                    \
  __builtin_amdgcn_global_load_lds(                                          \
      (const __attribute__((address_space(1))) void*)(gsrc),                 \
      (__attribute__((address_space(3))) void*)(ldst), 4, 0, 0)

// ---------------------------------------------------------------------------
// Bitonic sort of 64 (val,idx) pairs across the wave, DESCENDING by
// (val desc, idx asc). 21 compare-exchange steps. After: lane r = rank r.
// ---------------------------------------------------------------------------
__device__ __forceinline__ void bitonic64_desc(float& v, int& i) {
  const int lane = threadIdx.x & 63;
#pragma unroll
  for (int k = 2; k <= 64; k <<= 1) {
#pragma unroll
    for (int j = 64; j > 0; j >>= 1) {
      if (j > (k >> 1)) continue;        // compile-time pruned
      float ov = __shfl_xor(v, j);
      int oi = __shfl_xor(i, j);
      const bool up = (lane & k) == 0;
      const bool lower = (lane & j) == 0;
      const bool mineFirst = (v > ov) || (v == ov && i < oi);
      const bool keep = (up == lower) ? mineFirst : !mineFirst;
      if (!keep) { v = ov; i = oi; }
    }
  }
}

// ---------------------------------------------------------------------------
// fp32 GEMM core (VERBATIM R5/R6 — bit-exact contract). Q/K projections only.
// ---------------------------------------------------------------------------
#define BM 128
#define BN 128
#define BK 16
#define LDP 132

__device__ __forceinline__ int bgran(int g) {
  return (g & ~7) | ((g + (g >> 3)) & 7);
}

__device__ __forceinline__ void gemm_core(const float* __restrict__ A,
                                          const float* __restrict__ Bm,
                                          int m0, int n0, int K,
                                          float (&acc)[8][8]) {
  __shared__ float As[BK * LDP];
  __shared__ float Bs[BK * LDP];

  const int t = threadIdx.x;
  const int tx = t & 15, ty = t >> 4;
  const int rs = t >> 2;
  const int cs = t & 3;

  float4 pa[2], pb[2];
#pragma unroll
  for (int it = 0; it < 2; ++it) {
    pa[it] = *(const float4*)(A + (long)(m0 + rs + 64 * it) * K + cs * 4);
    pb[it] = *(const float4*)(Bm + (long)(n0 + rs + 64 * it) * K + cs * 4);
  }

  for (int k0 = 0; k0 < K; k0 += BK) {
    __syncthreads();
    {
      const int sa = ((cs & 1) << 2);
      const int base = cs * 4 * LDP;
#pragma unroll
      for (int it = 0; it < 2; ++it) {
        const int r = rs + 64 * it;
        const int ra = r ^ sa;
        As[base + 0 * LDP + ra] = pa[it].x;
        As[base + 1 * LDP + ra] = pa[it].y;
        As[base + 2 * LDP + ra] = pa[it].z;
        As[base + 3 * LDP + ra] = pa[it].w;
        const int rb = bgran(r >> 2) * 4 + (r & 3);
        Bs[base + 0 * LDP + rb] = pb[it].x;
        Bs[base + 1 * LDP + rb] = pb[it].y;
        Bs[base + 2 * LDP + rb] = pb[it].z;
        Bs[base + 3 * LDP + rb] = pb[it].w;
      }
    }
    __syncthreads();

    if (k0 + BK < K) {
#pragma unroll
      for (int it = 0; it < 2; ++it) {
        pa[it] = *(const float4*)(A + (long)(m0 + rs + 64 * it) * K + k0 + BK + cs * 4);
        pb[it] = *(const float4*)(Bm + (long)(n0 + rs + 64 * it) * K + k0 + BK + cs * 4);
      }
    }

#pragma unroll
    for (int kk = 0; kk < BK; ++kk) {
      const int c1 = (kk >> 2) & 1;
      float a[8], b[8];
      {
        float4 u = *(const float4*)&As[kk * LDP + ty * 8 + c1 * 4];
        float4 v = *(const float4*)&As[kk * LDP + ty * 8 + 4 - c1 * 4];
        a[0] = u.x; a[1] = u.y; a[2] = u.z; a[3] = u.w;
        a[4] = v.x; a[5] = v.y; a[6] = v.z; a[7] = v.w;
        float4 p = *(const float4*)&Bs[kk * LDP + bgran(2 * tx) * 4];
        float4 q = *(const float4*)&Bs[kk * LDP + bgran(2 * tx + 1) * 4];
        b[0] = p.x; b[1] = p.y; b[2] = p.z; b[3] = p.w;
        b[4] = q.x; b[5] = q.y; b[6] = q.z; b[7] = q.w;
      }
#pragma unroll
      for (int i = 0; i < 8; ++i)
#pragma unroll
        for (int j = 0; j < 8; ++j) acc[i][j] = fmaf(a[i], b[j], acc[i][j]);
    }
  }
}

__device__ __forceinline__ void proj_epilogue(float* __restrict__ dst,
                                              const float* __restrict__ bvec,
                                              int m0, int n0, float (&acc)[8][8]) {
  const int t = threadIdx.x;
  const int tx = t & 15, ty = t >> 4;
#pragma unroll
  for (int i = 0; i < 8; ++i) {
    float* crow = dst + (long)(m0 + ty * 8 + i) * D_ + n0 + tx * 8;
    const float* bp = bvec + n0 + tx * 8;
    float4 r0, r1;
    r0.x = acc[i][0] + bp[0]; r0.y = acc[i][1] + bp[1];
    r0.z = acc[i][2] + bp[2]; r0.w = acc[i][3] + bp[3];
    r1.x = acc[i][4] + bp[4]; r1.y = acc[i][5] + bp[5];
    r1.z = acc[i][6] + bp[6]; r1.w = acc[i][7] + bp[7];
    ((float4*)crow)[0] = r0;
    ((float4*)crow)[1] = r1;
  }
}

// ---- Q,K projections: z = mat*8 + band, mat in {0,1} -----------------------
// R22: __launch_bounds__(256,4) — 92 VGPRs used <= 128 cap -> 4 waves/EU.
__global__ __launch_bounds__(256, 4) void gemm_proj_qk(Ptrs8 bands,
                                                       const float* __restrict__ qW,
                                                       const float* __restrict__ kW,
                                                       const float* __restrict__ qb,
                                                       const float* __restrict__ kb,
                                                       float* __restrict__ Qn,
                                                       float* __restrict__ Kn) {
  const int mat = blockIdx.z >> 3, band = blockIdx.z & 7;
  const float* W = (mat == 0) ? qW : kW;
  const float* bvec = (mat == 0) ? qb : kb;
  float* dst = ((mat == 0) ? Qn : Kn) + (long)band * BAND_ELEMS;
  W += (long)band * D_ * D_;
  bvec += band * D_;

  const int m0 = blockIdx.y * BM, n0 = blockIdx.x * BN;
  float acc[8][8] = {};
  gemm_core(bands.p[band], W, m0, n0, D_, acc);
  proj_epilogue(dst, bvec, m0, n0, acc);
}

// ---- V projection via bf16 split-2 MFMA (VERBATIM R16) ---------------------
__global__ __launch_bounds__(256) void gemm_proj_v_mfma(Ptrs8 bands,
                                                        const float* __restrict__ vW,
                                                        const float* __restrict__ vb,
                                                        float* __restrict__ V) {
  __shared__ ushort plds[4 * 4096];

  const int band = blockIdx.z;
  const uint* Au = (const uint*)bands.p[band];
  const uint* Bu = (const uint*)(vW + (long)band * D_ * D_);
  const float* bvec = vb + band * D_;
  float* dst = V + (long)band * BAND_ELEMS;

  const int t = threadIdx.x;
  const int lane = t & 63;
  const int wave = t >> 6;
  const int wm = wave >> 1, wn = wave & 1;
  const int fr = lane & 15, fh = lane >> 4;
  const int m0 = blockIdx.y * BM, n0 = blockIdx.x * BN;

  f32x4 acc[4][4] = {};

  const int sg_r[2] = {t >> 2, (t + 256) >> 2};
  const int sg_h = t & 3;

  for (int k0 = 0; k0 < D_; k0 += 32) {
    uint4 ga[2][2], gb[2][2];
#pragma unroll
    for (int it = 0; it < 2; ++it) {
      long offA = (long)(m0 + sg_r[it]) * D_ + k0 + sg_h * 8;
      ga[it][0] = *(const uint4*)(Au + offA);
      ga[it][1] = *(const uint4*)(Au + offA + 4);
      long offB = (long)(n0 + sg_r[it]) * D_ + k0 + sg_h * 8;
      gb[it][0] = *(const uint4*)(Bu + offB);
      gb[it][1] = *(const uint4*)(Bu + offB + 4);
    }
    __syncthreads();
#pragma unroll
    for (int op = 0; op < 2; ++op) {
#pragma unroll
      for (int it = 0; it < 2; ++it) {
        uint w[8];
        {
          uint4 w0 = op ? gb[it][0] : ga[it][0];
          uint4 w1 = op ? gb[it][1] : ga[it][1];
          w[0] = w0.x; w[1] = w0.y; w[2] = w0.z; w[3] = w0.w;
          w[4] = w1.x; w[5] = w1.y; w[6] = w1.z; w[7] = w1.w;
        }
        ushort8 vhi, vlo;
#pragma unroll
        for (int e = 0; e < 8; ++e) {
          float x = __uint_as_float(w[e]);
          ushort hb = f2bf_rne(x);
          ushort lb = f2bf_rne(x - bf2f(hb));
          vhi[e] = hb;
          vlo[e] = lb;
        }
        const int ds2 = (sg_h * 128 + sg_r[it]) * 8;
        *(ushort8*)&plds[op * 4096 + ds2] = vhi;
        *(ushort8*)&plds[(2 + op) * 4096 + ds2] = vlo;
      }
    }
    __syncthreads();

    bf16x8 ah[4], bh[4], al[4], bl[4];
#pragma unroll
    for (int i = 0; i < 4; ++i) {
      const int ra = wm * 64 + i * 16 + fr;
      const int rb = wn * 64 + i * 16 + fr;
      ah[i] = *(const bf16x8*)&plds[0 * 4096 + (fh * 128 + ra) * 8];
      bh[i] = *(const bf16x8*)&plds[1 * 4096 + (fh * 128 + rb) * 8];
      al[i] = *(const bf16x8*)&plds[2 * 4096 + (fh * 128 + ra) * 8];
      bl[i] = *(const bf16x8*)&plds[3 * 4096 + (fh * 128 + rb) * 8];
    }

#pragma unroll
    for (int i = 0; i < 4; ++i)
#pragma unroll
      for (int j = 0; j < 4; ++j) {
        acc[i][j] = __builtin_amdgcn_mfma_f32_16x16x32_bf16(ah[i], bh[j], acc[i][j], 0, 0, 0);
        acc[i][j] = __builtin_amdgcn_mfma_f32_16x16x32_bf16(ah[i], bl[j], acc[i][j], 0, 0, 0);
        acc[i][j] = __builtin_amdgcn_mfma_f32_16x16x32_bf16(al[i], bh[j], acc[i][j], 0, 0, 0);
      }
  }

#pragma unroll
  for (int i = 0; i < 4; ++i)
#pragma unroll
    for (int j = 0; j < 4; ++j) {
      const int col = n0 + wn * 64 + j * 16 + fr;
      const float bv = bvec[col];
#pragma unroll
      for (int r = 0; r < 4; ++r) {
        const int row = m0 + wm * 64 + i * 16 + fh * 4 + r;
        dst[(long)row * D_ + col] = acc[i][j][r] + bv;
      }
    }
}

// ---- L2 normalization + bf16 emission (VERBATIM R13) ------------------------
__global__ __launch_bounds__(256) void l2norm_rows(float* __restrict__ X,
                                                   ushort* __restrict__ bf) {
  const long row = (long)blockIdx.x * 4 + (threadIdx.x >> 6);
  const int lane = threadIdx.x & 63;
  float* p = X + row * D_;
  float4 a = ((float4*)p)[lane];
  float4 b = ((float4*)p)[lane + 64];
  float s = a.x * a.x + a.y * a.y + a.z * a.z + a.w * a.w +
            b.x * b.x + b.y * b.y + b.z * b.z + b.w * b.w;
#pragma unroll
  for (int m = 1; m < 64; m <<= 1) s += __shfl_xor(s, m);
  const float inv = 1.0f / fmaxf(sqrtf(s), 1e-12f);
  a.x *= inv; a.y *= inv; a.z *= inv; a.w *= inv;
  b.x *= inv; b.y *= inv; b.z *= inv; b.w *= inv;
  ((float4*)p)[lane] = a;
  ((float4*)p)[lane + 64] = b;
  ushort4 w0, w1;
  w0.x = f2bf_rne(a.x); w0.y = f2bf_rne(a.y); w0.z = f2bf_rne(a.z); w0.w = f2bf_rne(a.w);
  w1.x = f2bf_rne(b.x); w1.y = f2bf_rne(b.y); w1.z = f2bf_rne(b.z); w1.w = f2bf_rne(b.w);
  *(ushort4*)(bf + row * D_ + lane * 4) = w0;
  *(ushort4*)(bf + row * D_ + 256 + lane * 4) = w1;
}

// ---------------------------------------------------------------------------
// STAGE 1 (R22): same as R21; __launch_bounds__(256,3) raises the occupancy
// target (VGPR cap 170 >= ~168 used incl. accumulators -> 3 waves/EU).
// ---------------------------------------------------------------------------
#define SBM 128
#define SBN 128

__device__ __forceinline__ int gidx(int row, int oct) {
  return row * 4 + (oct ^ ((row >> 1) & 3));
}

__global__ __launch_bounds__(256, 3) void mfma_extract_bf(const ushort* __restrict__ Qbf,
                                                          const ushort* __restrict__ Kbf,
                                                          float* __restrict__ candv,
                                                          ushort* __restrict__ candi,
                                                          CallTab tab) {
  __shared__ ushort lds[3][2][4096];   // 48 KB

  const int z = blockIdx.z;
  const int c = z >> 3, b = z & 7;
  const ushort* A = Qbf + (long)tab.qi[c] * BAND_ELEMS + (long)b * N_ * D_;
  const ushort* Bm = Kbf + (long)tab.ki[c] * BAND_ELEMS + (long)b * N_ * D_;
  const int m0 = blockIdx.y * SBM, n0 = blockIdx.x * SBN;

  const int t = threadIdx.x;
  const int lane = t & 63;
  const int wm = t >> 6;
  const int fr = lane & 15, fh = lane >> 4;

  f32x4 acc[2][8] = {};

  const int srow = lane >> 2;
  const int soct = lane & 3;
  const ushort* sA[2];
  const ushort* sB[2];
  int dof[2];
#pragma unroll
  for (int it = 0; it < 2; ++it) {
    const int row0 = wm * 32 + it * 16;
    const int row = row0 + srow;
    const int oct = soct ^ ((row >> 1) & 3);
    sA[it] = A + (long)(m0 + row) * D_ + oct * 8;
    sB[it] = Bm + (long)(n0 + row) * D_ + oct * 8;
    dof[it] = row0 * 32;
  }

  int gofA[2], gofB[8];
#pragma unroll
  for (int i = 0; i < 2; ++i) gofA[i] = gidx(wm * 32 + i * 16 + fr, fh) * 8;
#pragma unroll
  for (int j = 0; j < 8; ++j) gofB[j] = gidx(j * 16 + fr, fh) * 8;

  ushort* lb = &lds[0][0][0];

#define XSTAGE(buf, m)                                                        \
  do {                                                                        \
    GLOAD16(sA[0] + (m) * 32, lb + ((buf) * 2 + 0) * 4096 + dof[0]);          \
    GLOAD16(sB[0] + (m) * 32, lb + ((buf) * 2 + 1) * 4096 + dof[0]);          \
    GLOAD16(sA[1] + (m) * 32, lb + ((buf) * 2 + 0) * 4096 + dof[1]);          \
    GLOAD16(sB[1] + (m) * 32, lb + ((buf) * 2 + 1) * 4096 + dof[1]);          \
  } while (0)

  XSTAGE(0, 0);
  XSTAGE(1, 1);

#pragma unroll
  for (int kq = 0; kq < 16; ++kq) {
    if (kq < 15) {
      asm volatile("s_waitcnt vmcnt(4)" ::: "memory");   // own stage kq retired
    } else {
      asm volatile("s_waitcnt vmcnt(0)" ::: "memory");
    }
    __builtin_amdgcn_sched_barrier(0);
    __builtin_amdgcn_s_barrier();          // all waves' stage-kq loads retired
    __builtin_amdgcn_sched_barrier(0);

    if (kq + 2 < 16) XSTAGE((kq + 2) % 3, kq + 2);   // overwrites buf (kq-1)%3

    const int ph = kq % 3;
    bf16x8 af[2], bfr[8];
#pragma unroll
    for (int i = 0; i < 2; ++i)
      af[i] = *(const bf16x8*)(lb + (ph * 2 + 0) * 4096 + gofA[i]);
#pragma unroll
    for (int j = 0; j < 8; ++j)
      bfr[j] = *(const bf16x8*)(lb + (ph * 2 + 1) * 4096 + gofB[j]);

#pragma unroll
    for (int i = 0; i < 2; ++i)
#pragma unroll
      for (int j = 0; j < 8; ++j)
        acc[i][j] = __builtin_amdgcn_mfma_f32_16x16x32_bf16(af[i], bfr[j], acc[i][j], 0, 0, 0);
  }
#undef XSTAGE

  // ---- per-tile top-8 extraction (VERBATIM R7) ----
#pragma unroll
  for (int i = 0; i < 2; ++i)
#pragma unroll
    for (int rr = 0; rr < 4; ++rr) {
      const int R = b * N_ + m0 + wm * 32 + i * 16 + fh * 4 + rr;
      const long base = (((long)c * 8192 + R) * 8 + blockIdx.x) * 8;
#pragma unroll
      for (int it = 0; it < 8; ++it) {
        float lv = acc[i][0][rr]; int lj = 0;
#pragma unroll
        for (int j = 1; j < 8; ++j)
          if (acc[i][j][rr] > lv) { lv = acc[i][j][rr]; lj = j; }
        int li = lj * 16 + fr;
#pragma unroll
        for (int m = 1; m < 16; m <<= 1) {
          float ov = __shfl_xor(lv, m);
          int oi = __shfl_xor(li, m);
          if (ov > lv || (ov == lv && oi < li)) { lv = ov; li = oi; }
        }
        if (fr == it) { candv[base + it] = lv; candi[base + it] = (ushort)(n0 + li); }
        if (fr == (li & 15)) {
#pragma unroll
          for (int j = 0; j < 8; ++j)
            if (j == (li >> 4)) acc[i][j][rr] = -INFINITY;
        }
      }
    }
}

// ---------------------------------------------------------------------------
// STAGE 2 (VERBATIM R20): exact fp32 chains + bitonic selection.
// ---------------------------------------------------------------------------
#define RRBLOCKS (NCALLS * 8192 / 4)       // 38912 = 8 * 4864

__global__ __launch_bounds__(256) void rerank_exact(const float* __restrict__ Qn,
                                                    const float* __restrict__ Kn,
                                                    const float* __restrict__ candv,
                                                    const ushort* __restrict__ candi,
                                                    float* __restrict__ fp,
                                                    int* __restrict__ fi,
                                                    float* __restrict__ out,
                                                    CallTab tab) {
  __shared__ float sbuf[4][2][1088];

  const int bid = blockIdx.x;
  const int blk = (bid & 7) * (RRBLOCKS / 8) + (bid >> 3);

  const int w = threadIdx.x >> 6, lane = threadIdx.x & 63;
  const long gr = (long)blk * 4 + w;
  const int c = (int)(gr >> 13);
  const int R = (int)(gr & 8191);
  const int b = R >> 10;

  const long cb = gr * 64;
  float cv = candv[cb + lane];
  int ci = (int)candi[cb + lane];

  bitonic64_desc(cv, ci);                 // lane r holds rank r
  const int mycand = lane & 15;
  const int eidx = __shfl(ci, mycand);

  const float* qrow = Qn + (long)tab.qi[c] * BAND_ELEMS + (long)R * D_;
  const float* ksrc0 = Kn + (long)tab.ki[c] * BAND_ELEMS +
                       ((long)(b << 10) + eidx) * D_ + ((lane >> 4) << 2);

#define STAGE(bb, ch)                                                         \
  do {                                                                        \
    float* base_ = &sbuf[w][bb][0];                                           \
    GLOAD16(ksrc0 + (ch) * 64 + 0,  base_ + 0);                               \
    GLOAD16(ksrc0 + (ch) * 64 + 16, base_ + 256);                             \
    GLOAD16(ksrc0 + (ch) * 64 + 32, base_ + 512);                             \
    GLOAD16(ksrc0 + (ch) * 64 + 48, base_ + 768);                             \
    GLOAD4(qrow + (ch) * 64 + lane, base_ + 1024);                            \
  } while (0)

  float acc = 0.f;
  STAGE(0, 0);
#pragma unroll
  for (int ch = 0; ch < 8; ++ch) {
    if (ch < 7) {
      STAGE((ch + 1) & 1, ch + 1);
      asm volatile("s_waitcnt vmcnt(5)" ::: "memory");
    } else {
      asm volatile("s_waitcnt vmcnt(0)" ::: "memory");
    }
    const float* kb2 = &sbuf[w][ch & 1][0];
    const float* qb2 = &sbuf[w][ch & 1][1024];
#pragma unroll
    for (int kq = 0; kq < 16; ++kq) {
      float4 kv = *(const float4*)(kb2 + kq * 64 + mycand * 4);
      float4 qv = *(const float4*)(qb2 + kq * 4);
      acc = fmaf(qv.x, kv.x, acc);
      acc = fmaf(qv.y, kv.y, acc);
      acc = fmaf(qv.z, kv.z, acc);
      acc = fmaf(qv.w, kv.w, acc);
    }
  }
#undef STAGE

  float ev = acc; int ei = eidx;
  bitonic64_desc(ev, ei);
  float sv[8]; int si[8];
#pragma unroll
  for (int j = 0; j < 8; ++j) {
    sv[j] = __shfl(ev, 4 * j);
    si[j] = __shfl(ei, 4 * j);
  }

  float p[8], sum = 0.f;
#pragma unroll
  for (int j = 0; j < 8; ++j) { p[j] = expf(sv[j] - sv[0]); sum += p[j]; }
  const float isum = 1.0f / sum;
  float H = 0.f;
#pragma unroll
  for (int j = 0; j < 8; ++j) { p[j] *= isum; H -= p[j] * logf(p[j] + 1e-9f); }

  if (lane == 0) {
    atomicAdd(out + OUT_MAIN + (long)c * B_ + b, H * (1.0f / (float)N_));
#pragma unroll
    for (int j = 0; j < 8; ++j) { fp[gr * 8 + j] = p[j]; fi[gr * 8 + j] = si[j]; }
  }
}

// ---- merge finals + PV + band add + out write (VERBATIM R7) -----------------
__global__ __launch_bounds__(256) void merge_pv(Ptrs8 bands,
                                                const float* __restrict__ fp,
                                                const int* __restrict__ fi,
                                                const float* __restrict__ V,
                                                float* __restrict__ out,
                                                MergeTab mt) {
  const int bb = blockIdx.y;
  const int w = threadIdx.x >> 6, lane = threadIdx.x & 63;
  const long R = (long)blockIdx.x * 4 + w;
  const int b = (int)(R >> 10);

  float4 o0 = {0, 0, 0, 0}, o1 = {0, 0, 0, 0};
  const int nc = mt.ncalls[bb];
  for (int s = 0; s < nc; ++s) {
    const int c = mt.calls[bb][s];
    const float wt = mt.wts[c];
    const int ki = mt.kis[c];
    const long fb = ((long)c * 8192 + R) * 8;
    float4 p0 = *(const float4*)(fp + fb);
    float4 p1 = *(const float4*)(fp + fb + 4);
    int4 i0 = *(const int4*)(fi + fb);
    int4 i1 = *(const int4*)(fi + fb + 4);
    float pj[8] = {p0.x, p0.y, p0.z, p0.w, p1.x, p1.y, p1.z, p1.w};
    int ij[8] = {i0.x, i0.y, i0.z, i0.w, i1.x, i1.y, i1.z, i1.w};
#pragma unroll
    for (int j = 0; j < 8; ++j) {
      const float pw = pj[j] * wt;
      const float4* vr = (const float4*)(V + (long)ki * BAND_ELEMS +
                                         ((long)(b << 10) + ij[j]) * D_);
      float4 x0 = vr[lane * 2], x1 = vr[lane * 2 + 1];
      o0.x += pw * x0.x; o0.y += pw * x0.y; o0.z += pw * x0.z; o0.w += pw * x0.w;
      o1.x += pw * x1.x; o1.y += pw * x1.y; o1.z += pw * x1.z; o1.w += pw * x1.w;
    }
  }

  const float4* src = (const float4*)(bands.p[bb] + R * D_);
  float4 s0 = src[lane * 2], s1 = src[lane * 2 + 1];
  s0.x += o0.x; s0.y += o0.y; s0.z += o0.z; s0.w += o0.w;
  s1.x += o1.x; s1.y += o1.y; s1.z += o1.z; s1.w += o1.w;
  float4* dst = (float4*)(out + (long)bb * BAND_ELEMS + R * D_);
  dst[lane * 2] = s0;
  dst[lane * 2 + 1] = s1;
}

// ---- zero the 152 entropy slots ---------------------------------------------
__global__ void init_eps(float* __restrict__ out) {
  if (threadIdx.x < NCALLS * B_) out[OUT_MAIN + threadIdx.x] = 0.f;
}

// --------------------------------------------------------------------------------
extern "C" void kernel_launch(void* const* d_in, const int* in_sizes, int n_in,
                              void* d_out, int out_size, void* d_ws, size_t ws_size,
                              hipStream_t stream) {
  Ptrs8 bands;
  for (int i = 0; i < 8; ++i) bands.p[i] = (const float*)d_in[i];
  const float* qW = (const float*)d_in[8];
  const float* qb = (const float*)d_in[9];
  const float* kW = (const float*)d_in[10];
  const float* kb = (const float*)d_in[11];
  const float* vW = (const float*)d_in[12];
  const float* vb = (const float*)d_in[13];
  float* out = (float*)d_out;
  float* ws = (float*)d_ws;

  float* Qn = ws;                                        // fp32, 134.2 MB
  float* Kn = ws + (long)8 * BAND_ELEMS;                 // fp32, 134.2 MB
  float* V = ws + (long)16 * BAND_ELEMS;                 // overlay: bf16 then V
  ushort* bfbuf = (ushort*)V;
  float* candv = ws + (long)24 * BAND_ELEMS;             // 39.9 MB
  ushort* candi = (ushort*)(candv + (long)NCALLS * 8192 * 64);  // 19.9 MB
  float* fp = (float*)(candi + (long)NCALLS * 8192 * 64);       // 5 MB
  int* fi = (int*)(fp + (long)NCALLS * 8192 * 8);               // 5 MB

  static const int calls[NCALLS][2] = {
      {6, 0}, {0, 6}, {5, 1}, {1, 5}, {4, 2}, {2, 4},
      {0, 3}, {1, 3}, {2, 3}, {4, 3}, {5, 3}, {6, 3},
      {0, 7}, {1, 7}, {2, 7}, {3, 7}, {4, 7}, {5, 7}, {6, 7}};

  CallTab tab;
  MergeTab mt;
  for (int i = 0; i < 8; ++i) mt.ncalls[i] = 0;
  for (int c = 0; c < NCALLS; ++c) {
    tab.qi[c] = calls[c][0];
    tab.ki[c] = calls[c][1];
    mt.kis[c] = calls[c][1];
    mt.wts[c] = (c < 6) ? 1.0f : 0.5f;
    int q = calls[c][0];
    mt.calls[q][mt.ncalls[q]++] = c;
  }

  hipLaunchKernelGGL(init_eps, dim3(1), dim3(256), 0, stream, out);

  dim3 gqk(D_ / BN, (B_ * N_) / BM, 16);
  hipLaunchKernelGGL(gemm_proj_qk, gqk, dim3(256), 0, stream,
                     bands, qW, kW, qb, kb, Qn, Kn);

  hipLaunchKernelGGL(l2norm_rows, dim3(2 * 8 * B_ * N_ / 4), dim3(256), 0, stream,
                     Qn, bfbuf);

  dim3 gs(N_ / SBN, N_ / SBM, NCALLS * 8);
  hipLaunchKernelGGL(mfma_extract_bf, gs, dim3(256), 0, stream,
                     bfbuf, bfbuf + (long)8 * BAND_ELEMS, candv, candi, tab);

  dim3 gv(D_ / BN, (B_ * N_) / BM, 8);
  hipLaunchKernelGGL(gemm_proj_v_mfma, gv, dim3(256), 0, stream, bands, vW, vb, V);

  hipLaunchKernelGGL(rerank_exact, dim3(RRBLOCKS), dim3(256), 0, stream,
                     Qn, Kn, candv, candi, fp, fi, out, tab);

  hipLaunchKernelGGL(merge_pv, dim3(B_ * N_ / 4, 8), dim3(256), 0, stream,
                     bands, fp, fi, V, out, mt);
}

// Round 23
// 2805.983 us; speedup vs baseline: 1.6934x; 1.6934x over previous
//
#include <hip/hip_runtime.h>
#include <math.h>

#define B_ 8
#define N_ 1024
#define D_ 512
#define BAND_ELEMS (B_ * N_ * D_)          // 4194304 = 2^22
#define OUT_MAIN (8L * BAND_ELEMS)         // 33554432
#define NCALLS 19

struct Ptrs8 { const float* p[8]; };
struct CallTab { int qi[NCALLS]; int ki[NCALLS]; };
struct MergeTab { int ncalls[8]; int calls[8][3]; int kis[NCALLS]; float wts[NCALLS]; };

typedef __attribute__((ext_vector_type(8))) short bf16x8;
typedef __attribute__((ext_vector_type(8))) ushort ushort8;
typedef __attribute__((ext_vector_type(4))) float f32x4;

__device__ __forceinline__ ushort f2bf_rne(float x) {
  uint u = __float_as_uint(x);
  return (ushort)((u + 0x7fffu + ((u >> 16) & 1u)) >> 16);
}
__device__ __forceinline__ float bf2f(ushort h) {
  return __uint_as_float(((uint)h) << 16);
}

#define GLOAD16(gsrc, ldst)                                                   \
  __builtin_amdgcn_global_load_lds(                                          \
      (const __attribute__((address_space(1))) void*)(gsrc),                 \
      (__attribute__((address_space(3))) void*)(ldst), 16, 0, 0)
#define GLOAD4(gsrc, ldst)                                                    \
  __builtin_amdgcn_global_load_lds(                                          \
      (const __attribute__((address_space(1))) void*)(gsrc),                 \
      (__attribute__((address_space(3))) void*)(ldst), 4, 0, 0)

// ---------------------------------------------------------------------------
// Bitonic sort of 64 (val,idx) pairs across the wave, DESCENDING by
// (val desc, idx asc). 21 compare-exchange steps. After: lane r = rank r.
// ---------------------------------------------------------------------------
__device__ __forceinline__ void bitonic64_desc(float& v, int& i) {
  const int lane = threadIdx.x & 63;
#pragma unroll
  for (int k = 2; k <= 64; k <<= 1) {
#pragma unroll
    for (int j = 64; j > 0; j >>= 1) {
      if (j > (k >> 1)) continue;        // compile-time pruned
      float ov = __shfl_xor(v, j);
      int oi = __shfl_xor(i, j);
      const bool up = (lane & k) == 0;
      const bool lower = (lane & j) == 0;
      const bool mineFirst = (v > ov) || (v == ov && i < oi);
      const bool keep = (up == lower) ? mineFirst : !mineFirst;
      if (!keep) { v = ov; i = oi; }
    }
  }
}

// ---------------------------------------------------------------------------
// fp32 GEMM core (VERBATIM R5/R6 — bit-exact contract). Q/K projections only.
// ---------------------------------------------------------------------------
#define BM 128
#define BN 128
#define BK 16
#define LDP 132

__device__ __forceinline__ int bgran(int g) {
  return (g & ~7) | ((g + (g >> 3)) & 7);
}

__device__ __forceinline__ void gemm_core(const float* __restrict__ A,
                                          const float* __restrict__ Bm,
                                          int m0, int n0, int K,
                                          float (&acc)[8][8]) {
  __shared__ float As[BK * LDP];
  __shared__ float Bs[BK * LDP];

  const int t = threadIdx.x;
  const int tx = t & 15, ty = t >> 4;
  const int rs = t >> 2;
  const int cs = t & 3;

  float4 pa[2], pb[2];
#pragma unroll
  for (int it = 0; it < 2; ++it) {
    pa[it] = *(const float4*)(A + (long)(m0 + rs + 64 * it) * K + cs * 4);
    pb[it] = *(const float4*)(Bm + (long)(n0 + rs + 64 * it) * K + cs * 4);
  }

  for (int k0 = 0; k0 < K; k0 += BK) {
    __syncthreads();
    {
      const int sa = ((cs & 1) << 2);
      const int base = cs * 4 * LDP;
#pragma unroll
      for (int it = 0; it < 2; ++it) {
        const int r = rs + 64 * it;
        const int ra = r ^ sa;
        As[base + 0 * LDP + ra] = pa[it].x;
        As[base + 1 * LDP + ra] = pa[it].y;
        As[base + 2 * LDP + ra] = pa[it].z;
        As[base + 3 * LDP + ra] = pa[it].w;
        const int rb = bgran(r >> 2) * 4 + (r & 3);
        Bs[base + 0 * LDP + rb] = pb[it].x;
        Bs[base + 1 * LDP + rb] = pb[it].y;
        Bs[base + 2 * LDP + rb] = pb[it].z;
        Bs[base + 3 * LDP + rb] = pb[it].w;
      }
    }
    __syncthreads();

    if (k0 + BK < K) {
#pragma unroll
      for (int it = 0; it < 2; ++it) {
        pa[it] = *(const float4*)(A + (long)(m0 + rs + 64 * it) * K + k0 + BK + cs * 4);
        pb[it] = *(const float4*)(Bm + (long)(n0 + rs + 64 * it) * K + k0 + BK + cs * 4);
      }
    }

#pragma unroll
    for (int kk = 0; kk < BK; ++kk) {
      const int c1 = (kk >> 2) & 1;
      float a[8], b[8];
      {
        float4 u = *(const float4*)&As[kk * LDP + ty * 8 + c1 * 4];
        float4 v = *(const float4*)&As[kk * LDP + ty * 8 + 4 - c1 * 4];
        a[0] = u.x; a[1] = u.y; a[2] = u.z; a[3] = u.w;
        a[4] = v.x; a[5] = v.y; a[6] = v.z; a[7] = v.w;
        float4 p = *(const float4*)&Bs[kk * LDP + bgran(2 * tx) * 4];
        float4 q = *(const float4*)&Bs[kk * LDP + bgran(2 * tx + 1) * 4];
        b[0] = p.x; b[1] = p.y; b[2] = p.z; b[3] = p.w;
        b[4] = q.x; b[5] = q.y; b[6] = q.z; b[7] = q.w;
      }
#pragma unroll
      for (int i = 0; i < 8; ++i)
#pragma unroll
        for (int j = 0; j < 8; ++j) acc[i][j] = fmaf(a[i], b[j], acc[i][j]);
    }
  }
}

__device__ __forceinline__ void proj_epilogue(float* __restrict__ dst,
                                              const float* __restrict__ bvec,
                                              int m0, int n0, float (&acc)[8][8]) {
  const int t = threadIdx.x;
  const int tx = t & 15, ty = t >> 4;
#pragma unroll
  for (int i = 0; i < 8; ++i) {
    float* crow = dst + (long)(m0 + ty * 8 + i) * D_ + n0 + tx * 8;
    const float* bp = bvec + n0 + tx * 8;
    float4 r0, r1;
    r0.x = acc[i][0] + bp[0]; r0.y = acc[i][1] + bp[1];
    r0.z = acc[i][2] + bp[2]; r0.w = acc[i][3] + bp[3];
    r1.x = acc[i][4] + bp[4]; r1.y = acc[i][5] + bp[5];
    r1.z = acc[i][6] + bp[6]; r1.w = acc[i][7] + bp[7];
    ((float4*)crow)[0] = r0;
    ((float4*)crow)[1] = r1;
  }
}

// ---- Q,K projections: z = mat*8 + band, mat in {0,1} (plain bounds) --------
__global__ __launch_bounds__(256) void gemm_proj_qk(Ptrs8 bands,
                                                    const float* __restrict__ qW,
                                                    const float* __restrict__ kW,
                                                    const float* __restrict__ qb,
                                                    const float* __restrict__ kb,
                                                    float* __restrict__ Qn,
                                                    float* __restrict__ Kn) {
  const int mat = blockIdx.z >> 3, band = blockIdx.z & 7;
  const float* W = (mat == 0) ? qW : kW;
  const float* bvec = (mat == 0) ? qb : kb;
  float* dst = ((mat == 0) ? Qn : Kn) + (long)band * BAND_ELEMS;
  W += (long)band * D_ * D_;
  bvec += band * D_;

  const int m0 = blockIdx.y * BM, n0 = blockIdx.x * BN;
  float acc[8][8] = {};
  gemm_core(bands.p[band], W, m0, n0, D_, acc);
  proj_epilogue(dst, bvec, m0, n0, acc);
}

// ---- V projection via bf16 split-2 MFMA (VERBATIM R16) ---------------------
__global__ __launch_bounds__(256) void gemm_proj_v_mfma(Ptrs8 bands,
                                                        const float* __restrict__ vW,
                                                        const float* __restrict__ vb,
                                                        float* __restrict__ V) {
  __shared__ ushort plds[4 * 4096];

  const int band = blockIdx.z;
  const uint* Au = (const uint*)bands.p[band];
  const uint* Bu = (const uint*)(vW + (long)band * D_ * D_);
  const float* bvec = vb + band * D_;
  float* dst = V + (long)band * BAND_ELEMS;

  const int t = threadIdx.x;
  const int lane = t & 63;
  const int wave = t >> 6;
  const int wm = wave >> 1, wn = wave & 1;
  const int fr = lane & 15, fh = lane >> 4;
  const int m0 = blockIdx.y * BM, n0 = blockIdx.x * BN;

  f32x4 acc[4][4] = {};

  const int sg_r[2] = {t >> 2, (t + 256) >> 2};
  const int sg_h = t & 3;

  for (int k0 = 0; k0 < D_; k0 += 32) {
    uint4 ga[2][2], gb[2][2];
#pragma unroll
    for (int it = 0; it < 2; ++it) {
      long offA = (long)(m0 + sg_r[it]) * D_ + k0 + sg_h * 8;
      ga[it][0] = *(const uint4*)(Au + offA);
      ga[it][1] = *(const uint4*)(Au + offA + 4);
      long offB = (long)(n0 + sg_r[it]) * D_ + k0 + sg_h * 8;
      gb[it][0] = *(const uint4*)(Bu + offB);
      gb[it][1] = *(const uint4*)(Bu + offB + 4);
    }
    __syncthreads();
#pragma unroll
    for (int op = 0; op < 2; ++op) {
#pragma unroll
      for (int it = 0; it < 2; ++it) {
        uint w[8];
        {
          uint4 w0 = op ? gb[it][0] : ga[it][0];
          uint4 w1 = op ? gb[it][1] : ga[it][1];
          w[0] = w0.x; w[1] = w0.y; w[2] = w0.z; w[3] = w0.w;
          w[4] = w1.x; w[5] = w1.y; w[6] = w1.z; w[7] = w1.w;
        }
        ushort8 vhi, vlo;
#pragma unroll
        for (int e = 0; e < 8; ++e) {
          float x = __uint_as_float(w[e]);
          ushort hb = f2bf_rne(x);
          ushort lb = f2bf_rne(x - bf2f(hb));
          vhi[e] = hb;
          vlo[e] = lb;
        }
        const int ds2 = (sg_h * 128 + sg_r[it]) * 8;
        *(ushort8*)&plds[op * 4096 + ds2] = vhi;
        *(ushort8*)&plds[(2 + op) * 4096 + ds2] = vlo;
      }
    }
    __syncthreads();

    bf16x8 ah[4], bh[4], al[4], bl[4];
#pragma unroll
    for (int i = 0; i < 4; ++i) {
      const int ra = wm * 64 + i * 16 + fr;
      const int rb = wn * 64 + i * 16 + fr;
      ah[i] = *(const bf16x8*)&plds[0 * 4096 + (fh * 128 + ra) * 8];
      bh[i] = *(const bf16x8*)&plds[1 * 4096 + (fh * 128 + rb) * 8];
      al[i] = *(const bf16x8*)&plds[2 * 4096 + (fh * 128 + ra) * 8];
      bl[i] = *(const bf16x8*)&plds[3 * 4096 + (fh * 128 + rb) * 8];
    }

#pragma unroll
    for (int i = 0; i < 4; ++i)
#pragma unroll
      for (int j = 0; j < 4; ++j) {
        acc[i][j] = __builtin_amdgcn_mfma_f32_16x16x32_bf16(ah[i], bh[j], acc[i][j], 0, 0, 0);
        acc[i][j] = __builtin_amdgcn_mfma_f32_16x16x32_bf16(ah[i], bl[j], acc[i][j], 0, 0, 0);
        acc[i][j] = __builtin_amdgcn_mfma_f32_16x16x32_bf16(al[i], bh[j], acc[i][j], 0, 0, 0);
      }
  }

#pragma unroll
  for (int i = 0; i < 4; ++i)
#pragma unroll
    for (int j = 0; j < 4; ++j) {
      const int col = n0 + wn * 64 + j * 16 + fr;
      const float bv = bvec[col];
#pragma unroll
      for (int r = 0; r < 4; ++r) {
        const int row = m0 + wm * 64 + i * 16 + fh * 4 + r;
        dst[(long)row * D_ + col] = acc[i][j][r] + bv;
      }
    }
}

// ---- L2 normalization + bf16 emission (VERBATIM R13) ------------------------
__global__ __launch_bounds__(256) void l2norm_rows(float* __restrict__ X,
                                                   ushort* __restrict__ bf) {
  const long row = (long)blockIdx.x * 4 + (threadIdx.x >> 6);
  const int lane = threadIdx.x & 63;
  float* p = X + row * D_;
  float4 a = ((float4*)p)[lane];
  float4 b = ((float4*)p)[lane + 64];
  float s = a.x * a.x + a.y * a.y + a.z * a.z + a.w * a.w +
            b.x * b.x + b.y * b.y + b.z * b.z + b.w * b.w;
#pragma unroll
  for (int m = 1; m < 64; m <<= 1) s += __shfl_xor(s, m);
  const float inv = 1.0f / fmaxf(sqrtf(s), 1e-12f);
  a.x *= inv; a.y *= inv; a.z *= inv; a.w *= inv;
  b.x *= inv; b.y *= inv; b.z *= inv; b.w *= inv;
  ((float4*)p)[lane] = a;
  ((float4*)p)[lane + 64] = b;
  ushort4 w0, w1;
  w0.x = f2bf_rne(a.x); w0.y = f2bf_rne(a.y); w0.z = f2bf_rne(a.z); w0.w = f2bf_rne(a.w);
  w1.x = f2bf_rne(b.x); w1.y = f2bf_rne(b.y); w1.z = f2bf_rne(b.z); w1.w = f2bf_rne(b.w);
  *(ushort4*)(bf + row * D_ + lane * 4) = w0;
  *(ushort4*)(bf + row * D_ + 256 + lane * 4) = w1;
}

// ---------------------------------------------------------------------------
// STAGE 1 (VERBATIM R21): bf16 MFMA approx scores + per-tile top-8; 3-buffer
// single-barrier pipeline.
// ---------------------------------------------------------------------------
#define SBM 128
#define SBN 128

__device__ __forceinline__ int gidx(int row, int oct) {
  return row * 4 + (oct ^ ((row >> 1) & 3));
}

__global__ __launch_bounds__(256) void mfma_extract_bf(const ushort* __restrict__ Qbf,
                                                       const ushort* __restrict__ Kbf,
                                                       float* __restrict__ candv,
                                                       ushort* __restrict__ candi,
                                                       CallTab tab) {
  __shared__ ushort lds[3][2][4096];   // 48 KB

  const int z = blockIdx.z;
  const int c = z >> 3, b = z & 7;
  const ushort* A = Qbf + (long)tab.qi[c] * BAND_ELEMS + (long)b * N_ * D_;
  const ushort* Bm = Kbf + (long)tab.ki[c] * BAND_ELEMS + (long)b * N_ * D_;
  const int m0 = blockIdx.y * SBM, n0 = blockIdx.x * SBN;

  const int t = threadIdx.x;
  const int lane = t & 63;
  const int wm = t >> 6;
  const int fr = lane & 15, fh = lane >> 4;

  f32x4 acc[2][8] = {};

  const int srow = lane >> 2;
  const int soct = lane & 3;
  const ushort* sA[2];
  const ushort* sB[2];
  int dof[2];
#pragma unroll
  for (int it = 0; it < 2; ++it) {
    const int row0 = wm * 32 + it * 16;
    const int row = row0 + srow;
    const int oct = soct ^ ((row >> 1) & 3);
    sA[it] = A + (long)(m0 + row) * D_ + oct * 8;
    sB[it] = Bm + (long)(n0 + row) * D_ + oct * 8;
    dof[it] = row0 * 32;
  }

  int gofA[2], gofB[8];
#pragma unroll
  for (int i = 0; i < 2; ++i) gofA[i] = gidx(wm * 32 + i * 16 + fr, fh) * 8;
#pragma unroll
  for (int j = 0; j < 8; ++j) gofB[j] = gidx(j * 16 + fr, fh) * 8;

  ushort* lb = &lds[0][0][0];

#define XSTAGE(buf, m)                                                        \
  do {                                                                        \
    GLOAD16(sA[0] + (m) * 32, lb + ((buf) * 2 + 0) * 4096 + dof[0]);          \
    GLOAD16(sB[0] + (m) * 32, lb + ((buf) * 2 + 1) * 4096 + dof[0]);          \
    GLOAD16(sA[1] + (m) * 32, lb + ((buf) * 2 + 0) * 4096 + dof[1]);          \
    GLOAD16(sB[1] + (m) * 32, lb + ((buf) * 2 + 1) * 4096 + dof[1]);          \
  } while (0)

  XSTAGE(0, 0);
  XSTAGE(1, 1);

#pragma unroll
  for (int kq = 0; kq < 16; ++kq) {
    if (kq < 15) {
      asm volatile("s_waitcnt vmcnt(4)" ::: "memory");   // own stage kq retired
    } else {
      asm volatile("s_waitcnt vmcnt(0)" ::: "memory");
    }
    __builtin_amdgcn_sched_barrier(0);
    __builtin_amdgcn_s_barrier();          // all waves' stage-kq loads retired
    __builtin_amdgcn_sched_barrier(0);

    if (kq + 2 < 16) XSTAGE((kq + 2) % 3, kq + 2);   // overwrites buf (kq-1)%3

    const int ph = kq % 3;
    bf16x8 af[2], bfr[8];
#pragma unroll
    for (int i = 0; i < 2; ++i)
      af[i] = *(const bf16x8*)(lb + (ph * 2 + 0) * 4096 + gofA[i]);
#pragma unroll
    for (int j = 0; j < 8; ++j)
      bfr[j] = *(const bf16x8*)(lb + (ph * 2 + 1) * 4096 + gofB[j]);

#pragma unroll
    for (int i = 0; i < 2; ++i)
#pragma unroll
      for (int j = 0; j < 8; ++j)
        acc[i][j] = __builtin_amdgcn_mfma_f32_16x16x32_bf16(af[i], bfr[j], acc[i][j], 0, 0, 0);
  }
#undef XSTAGE

  // ---- per-tile top-8 extraction (VERBATIM R7) ----
#pragma unroll
  for (int i = 0; i < 2; ++i)
#pragma unroll
    for (int rr = 0; rr < 4; ++rr) {
      const int R = b * N_ + m0 + wm * 32 + i * 16 + fh * 4 + rr;
      const long base = (((long)c * 8192 + R) * 8 + blockIdx.x) * 8;
#pragma unroll
      for (int it = 0; it < 8; ++it) {
        float lv = acc[i][0][rr]; int lj = 0;
#pragma unroll
        for (int j = 1; j < 8; ++j)
          if (acc[i][j][rr] > lv) { lv = acc[i][j][rr]; lj = j; }
        int li = lj * 16 + fr;
#pragma unroll
        for (int m = 1; m < 16; m <<= 1) {
          float ov = __shfl_xor(lv, m);
          int oi = __shfl_xor(li, m);
          if (ov > lv || (ov == lv && oi < li)) { lv = ov; li = oi; }
        }
        if (fr == it) { candv[base + it] = lv; candi[base + it] = (ushort)(n0 + li); }
        if (fr == (li & 15)) {
#pragma unroll
          for (int j = 0; j < 8; ++j)
            if (j == (li >> 4)) acc[i][j][rr] = -INFINITY;
        }
      }
    }
}

// ---------------------------------------------------------------------------
// STAGE 2 (VERBATIM R20): exact fp32 chains + bitonic selection.
// ---------------------------------------------------------------------------
#define RRBLOCKS (NCALLS * 8192 / 4)       // 38912 = 8 * 4864

__global__ __launch_bounds__(256) void rerank_exact(const float* __restrict__ Qn,
                                                    const float* __restrict__ Kn,
                                                    const float* __restrict__ candv,
                                                    const ushort* __restrict__ candi,
                                                    float* __restrict__ fp,
                                                    int* __restrict__ fi,
                                                    float* __restrict__ out,
                                                    CallTab tab) {
  __shared__ float sbuf[4][2][1088];

  const int bid = blockIdx.x;
  const int blk = (bid & 7) * (RRBLOCKS / 8) + (bid >> 3);

  const int w = threadIdx.x >> 6, lane = threadIdx.x & 63;
  const long gr = (long)blk * 4 + w;
  const int c = (int)(gr >> 13);
  const int R = (int)(gr & 8191);
  const int b = R >> 10;

  const long cb = gr * 64;
  float cv = candv[cb + lane];
  int ci = (int)candi[cb + lane];

  bitonic64_desc(cv, ci);                 // lane r holds rank r
  const int mycand = lane & 15;
  const int eidx = __shfl(ci, mycand);

  const float* qrow = Qn + (long)tab.qi[c] * BAND_ELEMS + (long)R * D_;
  const float* ksrc0 = Kn + (long)tab.ki[c] * BAND_ELEMS +
                       ((long)(b << 10) + eidx) * D_ + ((lane >> 4) << 2);

#define STAGE(bb, ch)                                                         \
  do {                                                                        \
    float* base_ = &sbuf[w][bb][0];                                           \
    GLOAD16(ksrc0 + (ch) * 64 + 0,  base_ + 0);                               \
    GLOAD16(ksrc0 + (ch) * 64 + 16, base_ + 256);                             \
    GLOAD16(ksrc0 + (ch) * 64 + 32, base_ + 512);                             \
    GLOAD16(ksrc0 + (ch) * 64 + 48, base_ + 768);                             \
    GLOAD4(qrow + (ch) * 64 + lane, base_ + 1024);                            \
  } while (0)

  float acc = 0.f;
  STAGE(0, 0);
#pragma unroll
  for (int ch = 0; ch < 8; ++ch) {
    if (ch < 7) {
      STAGE((ch + 1) & 1, ch + 1);
      asm volatile("s_waitcnt vmcnt(5)" ::: "memory");
    } else {
      asm volatile("s_waitcnt vmcnt(0)" ::: "memory");
    }
    const float* kb2 = &sbuf[w][ch & 1][0];
    const float* qb2 = &sbuf[w][ch & 1][1024];
#pragma unroll
    for (int kq = 0; kq < 16; ++kq) {
      float4 kv = *(const float4*)(kb2 + kq * 64 + mycand * 4);
      float4 qv = *(const float4*)(qb2 + kq * 4);
      acc = fmaf(qv.x, kv.x, acc);
      acc = fmaf(qv.y, kv.y, acc);
      acc = fmaf(qv.z, kv.z, acc);
      acc = fmaf(qv.w, kv.w, acc);
    }
  }
#undef STAGE

  float ev = acc; int ei = eidx;
  bitonic64_desc(ev, ei);
  float sv[8]; int si[8];
#pragma unroll
  for (int j = 0; j < 8; ++j) {
    sv[j] = __shfl(ev, 4 * j);
    si[j] = __shfl(ei, 4 * j);
  }

  float p[8], sum = 0.f;
#pragma unroll
  for (int j = 0; j < 8; ++j) { p[j] = expf(sv[j] - sv[0]); sum += p[j]; }
  const float isum = 1.0f / sum;
  float H = 0.f;
#pragma unroll
  for (int j = 0; j < 8; ++j) { p[j] *= isum; H -= p[j] * logf(p[j] + 1e-9f); }

  if (lane == 0) {
    atomicAdd(out + OUT_MAIN + (long)c * B_ + b, H * (1.0f / (float)N_));
#pragma unroll
    for (int j = 0; j < 8; ++j) { fp[gr * 8 + j] = p[j]; fi[gr * 8 + j] = si[j]; }
  }
}

// ---- merge finals + PV + band add + out write (VERBATIM R7) -----------------
__global__ __launch_bounds__(256) void merge_pv(Ptrs8 bands,
                                                const float* __restrict__ fp,
                                                const int* __restrict__ fi,
                                                const float* __restrict__ V,
                                                float* __restrict__ out,
                                                MergeTab mt) {
  const int bb = blockIdx.y;
  const int w = threadIdx.x >> 6, lane = threadIdx.x & 63;
  const long R = (long)blockIdx.x * 4 + w;
  const int b = (int)(R >> 10);

  float4 o0 = {0, 0, 0, 0}, o1 = {0, 0, 0, 0};
  const int nc = mt.ncalls[bb];
  for (int s = 0; s < nc; ++s) {
    const int c = mt.calls[bb][s];
    const float wt = mt.wts[c];
    const int ki = mt.kis[c];
    const long fb = ((long)c * 8192 + R) * 8;
    float4 p0 = *(const float4*)(fp + fb);
    float4 p1 = *(const float4*)(fp + fb + 4);
    int4 i0 = *(const int4*)(fi + fb);
    int4 i1 = *(const int4*)(fi + fb + 4);
    float pj[8] = {p0.x, p0.y, p0.z, p0.w, p1.x, p1.y, p1.z, p1.w};
    int ij[8] = {i0.x, i0.y, i0.z, i0.w, i1.x, i1.y, i1.z, i1.w};
#pragma unroll
    for (int j = 0; j < 8; ++j) {
      const float pw = pj[j] * wt;
      const float4* vr = (const float4*)(V + (long)ki * BAND_ELEMS +
                                         ((long)(b << 10) + ij[j]) * D_);
      float4 x0 = vr[lane * 2], x1 = vr[lane * 2 + 1];
      o0.x += pw * x0.x; o0.y += pw * x0.y; o0.z += pw * x0.z; o0.w += pw * x0.w;
      o1.x += pw * x1.x; o1.y += pw * x1.y; o1.z += pw * x1.z; o1.w += pw * x1.w;
    }
  }

  const float4* src = (const float4*)(bands.p[bb] + R * D_);
  float4 s0 = src[lane * 2], s1 = src[lane * 2 + 1];
  s0.x += o0.x; s0.y += o0.y; s0.z += o0.z; s0.w += o0.w;
  s1.x += o1.x; s1.y += o1.y; s1.z += o1.z; s1.w += o1.w;
  float4* dst = (float4*)(out + (long)bb * BAND_ELEMS + R * D_);
  dst[lane * 2] = s0;
  dst[lane * 2 + 1] = s1;
}

// ---- zero the 152 entropy slots ---------------------------------------------
__global__ void init_eps(float* __restrict__ out) {
  if (threadIdx.x < NCALLS * B_) out[OUT_MAIN + threadIdx.x] = 0.f;
}

// --------------------------------------------------------------------------------
extern "C" void kernel_launch(void* const* d_in, const int* in_sizes, int n_in,
                              void* d_out, int out_size, void* d_ws, size_t ws_size,
                              hipStream_t stream) {
  Ptrs8 bands;
  for (int i = 0; i < 8; ++i) bands.p[i] = (const float*)d_in[i];
  const float* qW = (const float*)d_in[8];
  const float* qb = (const float*)d_in[9];
  const float* kW = (const float*)d_in[10];
  const float* kb = (const float*)d_in[11];
  const float* vW = (const float*)d_in[12];
  const float* vb = (const float*)d_in[13];
  float* out = (float*)d_out;
  float* ws = (float*)d_ws;

  float* Qn = ws;                                        // fp32, 134.2 MB
  float* Kn = ws + (long)8 * BAND_ELEMS;                 // fp32, 134.2 MB
  float* V = ws + (long)16 * BAND_ELEMS;                 // overlay: bf16 then V
  ushort* bfbuf = (ushort*)V;
  float* candv = ws + (long)24 * BAND_ELEMS;             // 39.9 MB
  ushort* candi = (ushort*)(candv + (long)NCALLS * 8192 * 64);  // 19.9 MB
  float* fp = (float*)(candi + (long)NCALLS * 8192 * 64);       // 5 MB
  int* fi = (int*)(fp + (long)NCALLS * 8192 * 8);               // 5 MB

  static const int calls[NCALLS][2] = {
      {6, 0}, {0, 6}, {5, 1}, {1, 5}, {4, 2}, {2, 4},
      {0, 3}, {1, 3}, {2, 3}, {4, 3}, {5, 3}, {6, 3},
      {0, 7}, {1, 7}, {2, 7}, {3, 7}, {4, 7}, {5, 7}, {6, 7}};

  CallTab tab;
  MergeTab mt;
  for (int i = 0; i < 8; ++i) mt.ncalls[i] = 0;
  for (int c = 0; c < NCALLS; ++c) {
    tab.qi[c] = calls[c][0];
    tab.ki[c] = calls[c][1];
    mt.kis[c] = calls[c][1];
    mt.wts[c] = (c < 6) ? 1.0f : 0.5f;
    int q = calls[c][0];
    mt.calls[q][mt.ncalls[q]++] = c;
  }

  hipLaunchKernelGGL(init_eps, dim3(1), dim3(256), 0, stream, out);

  dim3 gqk(D_ / BN, (B_ * N_) / BM, 16);
  hipLaunchKernelGGL(gemm_proj_qk, gqk, dim3(256), 0, stream,
                     bands, qW, kW, qb, kb, Qn, Kn);

  hipLaunchKernelGGL(l2norm_rows, dim3(2 * 8 * B_ * N_ / 4), dim3(256), 0, stream,
                     Qn, bfbuf);

  dim3 gs(N_ / SBN, N_ / SBM, NCALLS * 8);
  hipLaunchKernelGGL(mfma_extract_bf, gs, dim3(256), 0, stream,
                     bfbuf, bfbuf + (long)8 * BAND_ELEMS, candv, candi, tab);

  dim3 gv(D_ / BN, (B_ * N_) / BM, 8);
  hipLaunchKernelGGL(gemm_proj_v_mfma, gv, dim3(256), 0, stream, bands, vW, vb, V);

  hipLaunchKernelGGL(rerank_exact, dim3(RRBLOCKS), dim3(256), 0, stream,
                     Qn, Kn, candv, candi, fp, fi, out, tab);

  hipLaunchKernelGGL(merge_pv, dim3(B_ * N_ / 4, 8), dim3(256), 0, stream,
                     bands, fp, fi, V, out, mt);
}

// Round 24
// 2764.959 us; speedup vs baseline: 1.7185x; 1.0148x over previous
//
#include <hip/hip_runtime.h>
#include <math.h>

#define B_ 8
#define N_ 1024
#define D_ 512
#define BAND_ELEMS (B_ * N_ * D_)          // 4194304 = 2^22
#define OUT_MAIN (8L * BAND_ELEMS)         // 33554432
#define NCALLS 19

struct Ptrs8 { const float* p[8]; };
struct CallTab { int qi[NCALLS]; int ki[NCALLS]; };
struct MergeTab { int ncalls[8]; int calls[8][3]; int kis[NCALLS]; float wts[NCALLS]; };

typedef __attribute__((ext_vector_type(8))) short bf16x8;
typedef __attribute__((ext_vector_type(8))) ushort ushort8;
typedef __attribute__((ext_vector_type(4))) float f32x4;

__device__ __forceinline__ ushort f2bf_rne(float x) {
  uint u = __float_as_uint(x);
  return (ushort)((u + 0x7fffu + ((u >> 16) & 1u)) >> 16);
}
__device__ __forceinline__ float bf2f(ushort h) {
  return __uint_as_float(((uint)h) << 16);
}

#define GLOAD16(gsrc, ldst)                                                   \
  __builtin_amdgcn_global_load_lds(                                          \
      (const __attribute__((address_space(1))) void*)(gsrc),                 \
      (__attribute__((address_space(3))) void*)(ldst), 16, 0, 0)
#define GLOAD4(gsrc, ldst)                                                    \
  __builtin_amdgcn_global_load_lds(                                          \
      (const __attribute__((address_space(1))) void*)(gsrc),                 \
      (__attribute__((address_space(3))) void*)(ldst), 4, 0, 0)

// ---------------------------------------------------------------------------
// Bitonic sort of 64 (val,idx) pairs across the wave, DESCENDING by
// (val desc, idx asc). 21 compare-exchange steps. After: lane r = rank r.
// ---------------------------------------------------------------------------
__device__ __forceinline__ void bitonic64_desc(float& v, int& i) {
  const int lane = threadIdx.x & 63;
#pragma unroll
  for (int k = 2; k <= 64; k <<= 1) {
#pragma unroll
    for (int j = 64; j > 0; j >>= 1) {
      if (j > (k >> 1)) continue;        // compile-time pruned
      float ov = __shfl_xor(v, j);
      int oi = __shfl_xor(i, j);
      const bool up = (lane & k) == 0;
      const bool lower = (lane & j) == 0;
      const bool mineFirst = (v > ov) || (v == ov && i < oi);
      const bool keep = (up == lower) ? mineFirst : !mineFirst;
      if (!keep) { v = ov; i = oi; }
    }
  }
}

// ---------------------------------------------------------------------------
// fp32 GEMM core (VERBATIM R5/R6 — bit-exact contract). Q/K projections only.
// ---------------------------------------------------------------------------
#define BM 128
#define BN 128
#define BK 16
#define LDP 132

__device__ __forceinline__ int bgran(int g) {
  return (g & ~7) | ((g + (g >> 3)) & 7);
}

__device__ __forceinline__ void gemm_core(const float* __restrict__ A,
                                          const float* __restrict__ Bm,
                                          int m0, int n0, int K,
                                          float (&acc)[8][8]) {
  __shared__ float As[BK * LDP];
  __shared__ float Bs[BK * LDP];

  const int t = threadIdx.x;
  const int tx = t & 15, ty = t >> 4;
  const int rs = t >> 2;
  const int cs = t & 3;

  float4 pa[2], pb[2];
#pragma unroll
  for (int it = 0; it < 2; ++it) {
    pa[it] = *(const float4*)(A + (long)(m0 + rs + 64 * it) * K + cs * 4);
    pb[it] = *(const float4*)(Bm + (long)(n0 + rs + 64 * it) * K + cs * 4);
  }

  for (int k0 = 0; k0 < K; k0 += BK) {
    __syncthreads();
    {
      const int sa = ((cs & 1) << 2);
      const int base = cs * 4 * LDP;
#pragma unroll
      for (int it = 0; it < 2; ++it) {
        const int r = rs + 64 * it;
        const int ra = r ^ sa;
        As[base + 0 * LDP + ra] = pa[it].x;
        As[base + 1 * LDP + ra] = pa[it].y;
        As[base + 2 * LDP + ra] = pa[it].z;
        As[base + 3 * LDP + ra] = pa[it].w;
        const int rb = bgran(r >> 2) * 4 + (r & 3);
        Bs[base + 0 * LDP + rb] = pb[it].x;
        Bs[base + 1 * LDP + rb] = pb[it].y;
        Bs[base + 2 * LDP + rb] = pb[it].z;
        Bs[base + 3 * LDP + rb] = pb[it].w;
      }
    }
    __syncthreads();

    if (k0 + BK < K) {
#pragma unroll
      for (int it = 0; it < 2; ++it) {
        pa[it] = *(const float4*)(A + (long)(m0 + rs + 64 * it) * K + k0 + BK + cs * 4);
        pb[it] = *(const float4*)(Bm + (long)(n0 + rs + 64 * it) * K + k0 + BK + cs * 4);
      }
    }

#pragma unroll
    for (int kk = 0; kk < BK; ++kk) {
      const int c1 = (kk >> 2) & 1;
      float a[8], b[8];
      {
        float4 u = *(const float4*)&As[kk * LDP + ty * 8 + c1 * 4];
        float4 v = *(const float4*)&As[kk * LDP + ty * 8 + 4 - c1 * 4];
        a[0] = u.x; a[1] = u.y; a[2] = u.z; a[3] = u.w;
        a[4] = v.x; a[5] = v.y; a[6] = v.z; a[7] = v.w;
        float4 p = *(const float4*)&Bs[kk * LDP + bgran(2 * tx) * 4];
        float4 q = *(const float4*)&Bs[kk * LDP + bgran(2 * tx + 1) * 4];
        b[0] = p.x; b[1] = p.y; b[2] = p.z; b[3] = p.w;
        b[4] = q.x; b[5] = q.y; b[6] = q.z; b[7] = q.w;
      }
#pragma unroll
      for (int i = 0; i < 8; ++i)
#pragma unroll
        for (int j = 0; j < 8; ++j) acc[i][j] = fmaf(a[i], b[j], acc[i][j]);
    }
  }
}

__device__ __forceinline__ void proj_epilogue(float* __restrict__ dst,
                                              const float* __restrict__ bvec,
                                              int m0, int n0, float (&acc)[8][8]) {
  const int t = threadIdx.x;
  const int tx = t & 15, ty = t >> 4;
#pragma unroll
  for (int i = 0; i < 8; ++i) {
    float* crow = dst + (long)(m0 + ty * 8 + i) * D_ + n0 + tx * 8;
    const float* bp = bvec + n0 + tx * 8;
    float4 r0, r1;
    r0.x = acc[i][0] + bp[0]; r0.y = acc[i][1] + bp[1];
    r0.z = acc[i][2] + bp[2]; r0.w = acc[i][3] + bp[3];
    r1.x = acc[i][4] + bp[4]; r1.y = acc[i][5] + bp[5];
    r1.z = acc[i][6] + bp[6]; r1.w = acc[i][7] + bp[7];
    ((float4*)crow)[0] = r0;
    ((float4*)crow)[1] = r1;
  }
}

// ---- Q,K projections: z = mat*8 + band, mat in {0,1} -----------------------
__global__ __launch_bounds__(256) void gemm_proj_qk(Ptrs8 bands,
                                                    const float* __restrict__ qW,
                                                    const float* __restrict__ kW,
                                                    const float* __restrict__ qb,
                                                    const float* __restrict__ kb,
                                                    float* __restrict__ Qn,
                                                    float* __restrict__ Kn) {
  const int mat = blockIdx.z >> 3, band = blockIdx.z & 7;
  const float* W = (mat == 0) ? qW : kW;
  const float* bvec = (mat == 0) ? qb : kb;
  float* dst = ((mat == 0) ? Qn : Kn) + (long)band * BAND_ELEMS;
  W += (long)band * D_ * D_;
  bvec += band * D_;

  const int m0 = blockIdx.y * BM, n0 = blockIdx.x * BN;
  float acc[8][8] = {};
  gemm_core(bands.p[band], W, m0, n0, D_, acc);
  proj_epilogue(dst, bvec, m0, n0, acc);
}

// ---- V projection via bf16 split-2 MFMA (VERBATIM R16) ---------------------
__global__ __launch_bounds__(256) void gemm_proj_v_mfma(Ptrs8 bands,
                                                        const float* __restrict__ vW,
                                                        const float* __restrict__ vb,
                                                        float* __restrict__ V) {
  __shared__ ushort plds[4 * 4096];

  const int band = blockIdx.z;
  const uint* Au = (const uint*)bands.p[band];
  const uint* Bu = (const uint*)(vW + (long)band * D_ * D_);
  const float* bvec = vb + band * D_;
  float* dst = V + (long)band * BAND_ELEMS;

  const int t = threadIdx.x;
  const int lane = t & 63;
  const int wave = t >> 6;
  const int wm = wave >> 1, wn = wave & 1;
  const int fr = lane & 15, fh = lane >> 4;
  const int m0 = blockIdx.y * BM, n0 = blockIdx.x * BN;

  f32x4 acc[4][4] = {};

  const int sg_r[2] = {t >> 2, (t + 256) >> 2};
  const int sg_h = t & 3;

  for (int k0 = 0; k0 < D_; k0 += 32) {
    uint4 ga[2][2], gb[2][2];
#pragma unroll
    for (int it = 0; it < 2; ++it) {
      long offA = (long)(m0 + sg_r[it]) * D_ + k0 + sg_h * 8;
      ga[it][0] = *(const uint4*)(Au + offA);
      ga[it][1] = *(const uint4*)(Au + offA + 4);
      long offB = (long)(n0 + sg_r[it]) * D_ + k0 + sg_h * 8;
      gb[it][0] = *(const uint4*)(Bu + offB);
      gb[it][1] = *(const uint4*)(Bu + offB + 4);
    }
    __syncthreads();
#pragma unroll
    for (int op = 0; op < 2; ++op) {
#pragma unroll
      for (int it = 0; it < 2; ++it) {
        uint w[8];
        {
          uint4 w0 = op ? gb[it][0] : ga[it][0];
          uint4 w1 = op ? gb[it][1] : ga[it][1];
          w[0] = w0.x; w[1] = w0.y; w[2] = w0.z; w[3] = w0.w;
          w[4] = w1.x; w[5] = w1.y; w[6] = w1.z; w[7] = w1.w;
        }
        ushort8 vhi, vlo;
#pragma unroll
        for (int e = 0; e < 8; ++e) {
          float x = __uint_as_float(w[e]);
          ushort hb = f2bf_rne(x);
          ushort lb = f2bf_rne(x - bf2f(hb));
          vhi[e] = hb;
          vlo[e] = lb;
        }
        const int ds2 = (sg_h * 128 + sg_r[it]) * 8;
        *(ushort8*)&plds[op * 4096 + ds2] = vhi;
        *(ushort8*)&plds[(2 + op) * 4096 + ds2] = vlo;
      }
    }
    __syncthreads();

    bf16x8 ah[4], bh[4], al[4], bl[4];
#pragma unroll
    for (int i = 0; i < 4; ++i) {
      const int ra = wm * 64 + i * 16 + fr;
      const int rb = wn * 64 + i * 16 + fr;
      ah[i] = *(const bf16x8*)&plds[0 * 4096 + (fh * 128 + ra) * 8];
      bh[i] = *(const bf16x8*)&plds[1 * 4096 + (fh * 128 + rb) * 8];
      al[i] = *(const bf16x8*)&plds[2 * 4096 + (fh * 128 + ra) * 8];
      bl[i] = *(const bf16x8*)&plds[3 * 4096 + (fh * 128 + rb) * 8];
    }

#pragma unroll
    for (int i = 0; i < 4; ++i)
#pragma unroll
      for (int j = 0; j < 4; ++j) {
        acc[i][j] = __builtin_amdgcn_mfma_f32_16x16x32_bf16(ah[i], bh[j], acc[i][j], 0, 0, 0);
        acc[i][j] = __builtin_amdgcn_mfma_f32_16x16x32_bf16(ah[i], bl[j], acc[i][j], 0, 0, 0);
        acc[i][j] = __builtin_amdgcn_mfma_f32_16x16x32_bf16(al[i], bh[j], acc[i][j], 0, 0, 0);
      }
  }

#pragma unroll
  for (int i = 0; i < 4; ++i)
#pragma unroll
    for (int j = 0; j < 4; ++j) {
      const int col = n0 + wn * 64 + j * 16 + fr;
      const float bv = bvec[col];
#pragma unroll
      for (int r = 0; r < 4; ++r) {
        const int row = m0 + wm * 64 + i * 16 + fh * 4 + r;
        dst[(long)row * D_ + col] = acc[i][j][r] + bv;
      }
    }
}

// ---- L2 normalization + bf16 emission (VERBATIM R13) ------------------------
__global__ __launch_bounds__(256) void l2norm_rows(float* __restrict__ X,
                                                   ushort* __restrict__ bf) {
  const long row = (long)blockIdx.x * 4 + (threadIdx.x >> 6);
  const int lane = threadIdx.x & 63;
  float* p = X + row * D_;
  float4 a = ((float4*)p)[lane];
  float4 b = ((float4*)p)[lane + 64];
  float s = a.x * a.x + a.y * a.y + a.z * a.z + a.w * a.w +
            b.x * b.x + b.y * b.y + b.z * b.z + b.w * b.w;
#pragma unroll
  for (int m = 1; m < 64; m <<= 1) s += __shfl_xor(s, m);
  const float inv = 1.0f / fmaxf(sqrtf(s), 1e-12f);
  a.x *= inv; a.y *= inv; a.z *= inv; a.w *= inv;
  b.x *= inv; b.y *= inv; b.z *= inv; b.w *= inv;
  ((float4*)p)[lane] = a;
  ((float4*)p)[lane + 64] = b;
  ushort4 w0, w1;
  w0.x = f2bf_rne(a.x); w0.y = f2bf_rne(a.y); w0.z = f2bf_rne(a.z); w0.w = f2bf_rne(a.w);
  w1.x = f2bf_rne(b.x); w1.y = f2bf_rne(b.y); w1.z = f2bf_rne(b.z); w1.w = f2bf_rne(b.w);
  *(ushort4*)(bf + row * D_ + lane * 4) = w0;
  *(ushort4*)(bf + row * D_ + 256 + lane * 4) = w1;
}

// ---------------------------------------------------------------------------
// STAGE 1 (R24): 256x128 tile, 512 threads (8 waves). Per-wave structure is
// IDENTICAL to R23 (32x128 output, acc[2][8], same frag reads/MFMAs, verbatim
// extraction epilogue) -> bit-identical candidates. Changes: A-tile 256 rows
// shared by 8 waves (panel traffic 2.49 -> 1.87 GB), LDS 72 KB -> 2 blocks/CU
// = 16 waves/CU (2x TLP). vmcnt: 3 loads/stage -> wait(3), tail (0).
// ---------------------------------------------------------------------------
#define SBM 256
#define SBN 128
#define APL 8192   // A plane ushorts (256 rows * 32)
#define BPL 4096   // B plane ushorts (128 rows * 32)

__device__ __forceinline__ int gidx(int row, int oct) {
  return row * 4 + (oct ^ ((row >> 1) & 3));
}

__global__ __launch_bounds__(512) void mfma_extract_bf(const ushort* __restrict__ Qbf,
                                                       const ushort* __restrict__ Kbf,
                                                       float* __restrict__ candv,
                                                       ushort* __restrict__ candi,
                                                       CallTab tab) {
  __shared__ ushort lds[3][APL + BPL];   // 72 KB

  const int z = blockIdx.z;
  const int c = z >> 3, b = z & 7;
  const ushort* A = Qbf + (long)tab.qi[c] * BAND_ELEMS + (long)b * N_ * D_;
  const ushort* Bm = Kbf + (long)tab.ki[c] * BAND_ELEMS + (long)b * N_ * D_;
  const int m0 = blockIdx.y * SBM, n0 = blockIdx.x * SBN;

  const int t = threadIdx.x;
  const int lane = t & 63;
  const int wm = t >> 6;               // wave 0..7; wave rows = m0 + wm*32 ..
  const int fr = lane & 15, fh = lane >> 4;

  f32x4 acc[2][8] = {};

  // staging: wave wm stages A rows wm*32..wm*32+31 (2 GLOAD16) and
  // B rows wm*16..wm*16+15 (1 GLOAD16); per-lane coalesced 64B sources.
  const int srow = lane >> 2;
  const int soct = lane & 3;
  const ushort* sA[2];
  const ushort* sB0;
  int dofA[2], dofB;
#pragma unroll
  for (int it = 0; it < 2; ++it) {
    const int row0 = wm * 32 + it * 16;
    const int row = row0 + srow;
    const int oct = soct ^ ((row >> 1) & 3);
    sA[it] = A + (long)(m0 + row) * D_ + oct * 8;
    dofA[it] = row0 * 32;
  }
  {
    const int row0 = wm * 16;
    const int row = row0 + srow;
    const int oct = soct ^ ((row >> 1) & 3);
    sB0 = Bm + (long)(n0 + row) * D_ + oct * 8;
    dofB = APL + row0 * 32;
  }

  int gofA[2], gofB[8];
#pragma unroll
  for (int i = 0; i < 2; ++i) gofA[i] = gidx(wm * 32 + i * 16 + fr, fh) * 8;
#pragma unroll
  for (int j = 0; j < 8; ++j) gofB[j] = APL + gidx(j * 16 + fr, fh) * 8;

  ushort* lb = &lds[0][0];

#define XSTAGE(buf, m)                                                        \
  do {                                                                        \
    GLOAD16(sA[0] + (m) * 32, lb + (buf) * (APL + BPL) + dofA[0]);            \
    GLOAD16(sA[1] + (m) * 32, lb + (buf) * (APL + BPL) + dofA[1]);            \
    GLOAD16(sB0 + (m) * 32, lb + (buf) * (APL + BPL) + dofB);                 \
  } while (0)

  XSTAGE(0, 0);
  XSTAGE(1, 1);

#pragma unroll
  for (int kq = 0; kq < 16; ++kq) {
    if (kq < 15) {
      asm volatile("s_waitcnt vmcnt(3)" ::: "memory");   // own stage kq retired
    } else {
      asm volatile("s_waitcnt vmcnt(0)" ::: "memory");
    }
    __builtin_amdgcn_sched_barrier(0);
    __builtin_amdgcn_s_barrier();          // all waves' stage-kq loads retired
    __builtin_amdgcn_sched_barrier(0);

    if (kq + 2 < 16) XSTAGE((kq + 2) % 3, kq + 2);   // overwrites buf (kq-1)%3

    const int ph = kq % 3;
    const int pb = ph * (APL + BPL);
    bf16x8 af[2], bfr[8];
#pragma unroll
    for (int i = 0; i < 2; ++i)
      af[i] = *(const bf16x8*)(lb + pb + gofA[i]);
#pragma unroll
    for (int j = 0; j < 8; ++j)
      bfr[j] = *(const bf16x8*)(lb + pb + gofB[j]);

#pragma unroll
    for (int i = 0; i < 2; ++i)
#pragma unroll
      for (int j = 0; j < 8; ++j)
        acc[i][j] = __builtin_amdgcn_mfma_f32_16x16x32_bf16(af[i], bfr[j], acc[i][j], 0, 0, 0);
  }
#undef XSTAGE

  // ---- per-tile top-8 extraction (VERBATIM comparator/order; rows from
  // m0 + wm*32, tile = blockIdx.x) ----
#pragma unroll
  for (int i = 0; i < 2; ++i)
#pragma unroll
    for (int rr = 0; rr < 4; ++rr) {
      const int R = b * N_ + m0 + wm * 32 + i * 16 + fh * 4 + rr;
      const long base = (((long)c * 8192 + R) * 8 + blockIdx.x) * 8;
#pragma unroll
      for (int it = 0; it < 8; ++it) {
        float lv = acc[i][0][rr]; int lj = 0;
#pragma unroll
        for (int j = 1; j < 8; ++j)
          if (acc[i][j][rr] > lv) { lv = acc[i][j][rr]; lj = j; }
        int li = lj * 16 + fr;
#pragma unroll
        for (int m = 1; m < 16; m <<= 1) {
          float ov = __shfl_xor(lv, m);
          int oi = __shfl_xor(li, m);
          if (ov > lv || (ov == lv && oi < li)) { lv = ov; li = oi; }
        }
        if (fr == it) { candv[base + it] = lv; candi[base + it] = (ushort)(n0 + li); }
        if (fr == (li & 15)) {
#pragma unroll
          for (int j = 0; j < 8; ++j)
            if (j == (li >> 4)) acc[i][j][rr] = -INFINITY;
        }
      }
    }
}

// ---------------------------------------------------------------------------
// STAGE 2 (VERBATIM R20): exact fp32 chains + bitonic selection.
// ---------------------------------------------------------------------------
#define RRBLOCKS (NCALLS * 8192 / 4)       // 38912 = 8 * 4864

__global__ __launch_bounds__(256) void rerank_exact(const float* __restrict__ Qn,
                                                    const float* __restrict__ Kn,
                                                    const float* __restrict__ candv,
                                                    const ushort* __restrict__ candi,
                                                    float* __restrict__ fp,
                                                    int* __restrict__ fi,
                                                    float* __restrict__ out,
                                                    CallTab tab) {
  __shared__ float sbuf[4][2][1088];

  const int bid = blockIdx.x;
  const int blk = (bid & 7) * (RRBLOCKS / 8) + (bid >> 3);

  const int w = threadIdx.x >> 6, lane = threadIdx.x & 63;
  const long gr = (long)blk * 4 + w;
  const int c = (int)(gr >> 13);
  const int R = (int)(gr & 8191);
  const int b = R >> 10;

  const long cb = gr * 64;
  float cv = candv[cb + lane];
  int ci = (int)candi[cb + lane];

  bitonic64_desc(cv, ci);                 // lane r holds rank r
  const int mycand = lane & 15;
  const int eidx = __shfl(ci, mycand);

  const float* qrow = Qn + (long)tab.qi[c] * BAND_ELEMS + (long)R * D_;
  const float* ksrc0 = Kn + (long)tab.ki[c] * BAND_ELEMS +
                       ((long)(b << 10) + eidx) * D_ + ((lane >> 4) << 2);

#define STAGE(bb, ch)                                                         \
  do {                                                                        \
    float* base_ = &sbuf[w][bb][0];                                           \
    GLOAD16(ksrc0 + (ch) * 64 + 0,  base_ + 0);                               \
    GLOAD16(ksrc0 + (ch) * 64 + 16, base_ + 256);                             \
    GLOAD16(ksrc0 + (ch) * 64 + 32, base_ + 512);                             \
    GLOAD16(ksrc0 + (ch) * 64 + 48, base_ + 768);                             \
    GLOAD4(qrow + (ch) * 64 + lane, base_ + 1024);                            \
  } while (0)

  float acc = 0.f;
  STAGE(0, 0);
#pragma unroll
  for (int ch = 0; ch < 8; ++ch) {
    if (ch < 7) {
      STAGE((ch + 1) & 1, ch + 1);
      asm volatile("s_waitcnt vmcnt(5)" ::: "memory");
    } else {
      asm volatile("s_waitcnt vmcnt(0)" ::: "memory");
    }
    const float* kb2 = &sbuf[w][ch & 1][0];
    const float* qb2 = &sbuf[w][ch & 1][1024];
#pragma unroll
    for (int kq = 0; kq < 16; ++kq) {
      float4 kv = *(const float4*)(kb2 + kq * 64 + mycand * 4);
      float4 qv = *(const float4*)(qb2 + kq * 4);
      acc = fmaf(qv.x, kv.x, acc);
      acc = fmaf(qv.y, kv.y, acc);
      acc = fmaf(qv.z, kv.z, acc);
      acc = fmaf(qv.w, kv.w, acc);
    }
  }
#undef STAGE

  float ev = acc; int ei = eidx;
  bitonic64_desc(ev, ei);
  float sv[8]; int si[8];
#pragma unroll
  for (int j = 0; j < 8; ++j) {
    sv[j] = __shfl(ev, 4 * j);
    si[j] = __shfl(ei, 4 * j);
  }

  float p[8], sum = 0.f;
#pragma unroll
  for (int j = 0; j < 8; ++j) { p[j] = expf(sv[j] - sv[0]); sum += p[j]; }
  const float isum = 1.0f / sum;
  float H = 0.f;
#pragma unroll
  for (int j = 0; j < 8; ++j) { p[j] *= isum; H -= p[j] * logf(p[j] + 1e-9f); }

  if (lane == 0) {
    atomicAdd(out + OUT_MAIN + (long)c * B_ + b, H * (1.0f / (float)N_));
#pragma unroll
    for (int j = 0; j < 8; ++j) { fp[gr * 8 + j] = p[j]; fi[gr * 8 + j] = si[j]; }
  }
}

// ---- merge finals + PV + band add + out write (VERBATIM R7) -----------------
__global__ __launch_bounds__(256) void merge_pv(Ptrs8 bands,
                                                const float* __restrict__ fp,
                                                const int* __restrict__ fi,
                                                const float* __restrict__ V,
                                                float* __restrict__ out,
                                                MergeTab mt) {
  const int bb = blockIdx.y;
  const int w = threadIdx.x >> 6, lane = threadIdx.x & 63;
  const long R = (long)blockIdx.x * 4 + w;
  const int b = (int)(R >> 10);

  float4 o0 = {0, 0, 0, 0}, o1 = {0, 0, 0, 0};
  const int nc = mt.ncalls[bb];
  for (int s = 0; s < nc; ++s) {
    const int c = mt.calls[bb][s];
    const float wt = mt.wts[c];
    const int ki = mt.kis[c];
    const long fb = ((long)c * 8192 + R) * 8;
    float4 p0 = *(const float4*)(fp + fb);
    float4 p1 = *(const float4*)(fp + fb + 4);
    int4 i0 = *(const int4*)(fi + fb);
    int4 i1 = *(const int4*)(fi + fb + 4);
    float pj[8] = {p0.x, p0.y, p0.z, p0.w, p1.x, p1.y, p1.z, p1.w};
    int ij[8] = {i0.x, i0.y, i0.z, i0.w, i1.x, i1.y, i1.z, i1.w};
#pragma unroll
    for (int j = 0; j < 8; ++j) {
      const float pw = pj[j] * wt;
      const float4* vr = (const float4*)(V + (long)ki * BAND_ELEMS +
                                         ((long)(b << 10) + ij[j]) * D_);
      float4 x0 = vr[lane * 2], x1 = vr[lane * 2 + 1];
      o0.x += pw * x0.x; o0.y += pw * x0.y; o0.z += pw * x0.z; o0.w += pw * x0.w;
      o1.x += pw * x1.x; o1.y += pw * x1.y; o1.z += pw * x1.z; o1.w += pw * x1.w;
    }
  }

  const float4* src = (const float4*)(bands.p[bb] + R * D_);
  float4 s0 = src[lane * 2], s1 = src[lane * 2 + 1];
  s0.x += o0.x; s0.y += o0.y; s0.z += o0.z; s0.w += o0.w;
  s1.x += o1.x; s1.y += o1.y; s1.z += o1.z; s1.w += o1.w;
  float4* dst = (float4*)(out + (long)bb * BAND_ELEMS + R * D_);
  dst[lane * 2] = s0;
  dst[lane * 2 + 1] = s1;
}

// ---- zero the 152 entropy slots ---------------------------------------------
__global__ void init_eps(float* __restrict__ out) {
  if (threadIdx.x < NCALLS * B_) out[OUT_MAIN + threadIdx.x] = 0.f;
}

// --------------------------------------------------------------------------------
extern "C" void kernel_launch(void* const* d_in, const int* in_sizes, int n_in,
                              void* d_out, int out_size, void* d_ws, size_t ws_size,
                              hipStream_t stream) {
  Ptrs8 bands;
  for (int i = 0; i < 8; ++i) bands.p[i] = (const float*)d_in[i];
  const float* qW = (const float*)d_in[8];
  const float* qb = (const float*)d_in[9];
  const float* kW = (const float*)d_in[10];
  const float* kb = (const float*)d_in[11];
  const float* vW = (const float*)d_in[12];
  const float* vb = (const float*)d_in[13];
  float* out = (float*)d_out;
  float* ws = (float*)d_ws;

  float* Qn = ws;                                        // fp32, 134.2 MB
  float* Kn = ws + (long)8 * BAND_ELEMS;                 // fp32, 134.2 MB
  float* V = ws + (long)16 * BAND_ELEMS;                 // overlay: bf16 then V
  ushort* bfbuf = (ushort*)V;
  float* candv = ws + (long)24 * BAND_ELEMS;             // 39.9 MB
  ushort* candi = (ushort*)(candv + (long)NCALLS * 8192 * 64);  // 19.9 MB
  float* fp = (float*)(candi + (long)NCALLS * 8192 * 64);       // 5 MB
  int* fi = (int*)(fp + (long)NCALLS * 8192 * 8);               // 5 MB

  static const int calls[NCALLS][2] = {
      {6, 0}, {0, 6}, {5, 1}, {1, 5}, {4, 2}, {2, 4},
      {0, 3}, {1, 3}, {2, 3}, {4, 3}, {5, 3}, {6, 3},
      {0, 7}, {1, 7}, {2, 7}, {3, 7}, {4, 7}, {5, 7}, {6, 7}};

  CallTab tab;
  MergeTab mt;
  for (int i = 0; i < 8; ++i) mt.ncalls[i] = 0;
  for (int c = 0; c < NCALLS; ++c) {
    tab.qi[c] = calls[c][0];
    tab.ki[c] = calls[c][1];
    mt.kis[c] = calls[c][1];
    mt.wts[c] = (c < 6) ? 1.0f : 0.5f;
    int q = calls[c][0];
    mt.calls[q][mt.ncalls[q]++] = c;
  }

  hipLaunchKernelGGL(init_eps, dim3(1), dim3(256), 0, stream, out);

  dim3 gqk(D_ / BN, (B_ * N_) / BM, 16);
  hipLaunchKernelGGL(gemm_proj_qk, gqk, dim3(256), 0, stream,
                     bands, qW, kW, qb, kb, Qn, Kn);

  hipLaunchKernelGGL(l2norm_rows, dim3(2 * 8 * B_ * N_ / 4), dim3(256), 0, stream,
                     Qn, bfbuf);

  // extract: 256x128 tiles, 512 threads
  dim3 gs(N_ / SBN, N_ / SBM, NCALLS * 8);   // (8, 4, 152)
  hipLaunchKernelGGL(mfma_extract_bf, gs, dim3(512), 0, stream,
                     bfbuf, bfbuf + (long)8 * BAND_ELEMS, candv, candi, tab);

  dim3 gv(D_ / BN, (B_ * N_) / BM, 8);
  hipLaunchKernelGGL(gemm_proj_v_mfma, gv, dim3(256), 0, stream, bands, vW, vb, V);

  hipLaunchKernelGGL(rerank_exact, dim3(RRBLOCKS), dim3(256), 0, stream,
                     Qn, Kn, candv, candi, fp, fi, out, tab);

  hipLaunchKernelGGL(merge_pv, dim3(B_ * N_ / 4, 8), dim3(256), 0, stream,
                     bands, fp, fi, V, out, mt);
}